// Round 7
// baseline (229.794 us; speedup 1.0000x reference)
//
#include <hip/hip_runtime.h>

typedef short bfx8 __attribute__((ext_vector_type(8)));
typedef float fx4 __attribute__((ext_vector_type(4)));

#define E_TILE 64

__device__ __forceinline__ short f2b(float f) {
  union { float f; unsigned u; } v; v.f = f;
  unsigned u = v.u;
  u += 0x7fffu + ((u >> 16) & 1u);   // RNE
  return (short)(u >> 16);
}
__device__ __forceinline__ float relu(float f) { return f > 0.f ? f : 0.f; }
__device__ __forceinline__ float asf(unsigned u) { union { unsigned u; float f; } v; v.u = u; return v.f; }
__device__ __forceinline__ unsigned asu(float f) { union { float f; unsigned u; } v; v.f = f; return v.u; }

// ---------------- prep: convert weights to bf16 in ws ----------------
// B1[n][k], n in [0,512): n<256 -> W1[n][k] (P part); n>=256 -> W1[n-256][256+k] (Q part)
__global__ void k_prep(const float* __restrict__ W1, const float* __restrict__ W2,
                       unsigned short* __restrict__ B1, unsigned short* __restrict__ W2b) {
  int t = blockIdx.x * 256 + threadIdx.x;
  if (t < 512 * 256) {
    int n = t >> 8, k = t & 255;
    float v = (n < 256) ? W1[n * 512 + k] : W1[(n - 256) * 512 + 256 + k];
    B1[t] = (unsigned short)f2b(v);
  } else if (t < 512 * 256 + 256 * 256) {
    int i = t - 512 * 256;
    W2b[i] = (unsigned short)f2b(W2[i]);
  }
}

// ---------------- node kernel: PQ[m][0:512] = x[m] @ B1^T (bf16), b1 folded into Q half ---
// v4: B1 held ENTIRELY in registers (bw[4][8]=128 VGPR/wave; 8 waves cover all
// 512 N). Persistent grid=256: B1 loaded once per block (preload phase, off the
// per-tile critical path), then ~3 node-tiles of pure LDS->MFMA work. Kills the
// per-ks dependent global B-loads that left round-6's waves stalled on L2
// latency. ~230 regs at (512,2) cap=256 -> no spill (rounds 3-5 lesson:
// never cap below demand). 1 block/CU (reg-bound).
__launch_bounds__(512, 2)
__global__ void k_node(const float* __restrict__ x, const unsigned short* __restrict__ B1,
                       const float* __restrict__ b1,
                       unsigned short* __restrict__ PQ, int n_nodes, int ntiles) {
  __shared__ __align__(16) short smA[64 * 264];   // 33.8 KB; aliased as smT[32*520] in epilogue
  short* smT = smA;
  const int tid = threadIdx.x;
  const int wave = tid >> 6, lane = tid & 63;
  const int lr = lane & 15, lg = lane >> 4;
  const int n0 = wave * 64;                       // this wave's N base (0..448)

  // ---- preload B1 fragments + bias (once per block) ----
  bfx8 bw[4][8];
  float bias[4];
#pragma unroll
  for (int nt = 0; nt < 4; ++nt) {
    int n = n0 + nt * 16 + lr;
    bias[nt] = (n >= 256) ? b1[n - 256] : 0.f;
#pragma unroll
    for (int ks = 0; ks < 8; ++ks)
      bw[nt][ks] = *(const bfx8*)(B1 + (size_t)n * 256 + ks * 32 + lg * 8);
  }

  for (int tile = blockIdx.x; tile < ntiles; tile += gridDim.x) {
    const int m0 = tile * 64;
    __syncthreads();                  // smA reuse boundary (prev epilogue reads done)

    // ---- stage A-tile: 64 rows x 256 cols fp32 -> bf16 (8 thr/row) ----
    {
      int r = tid >> 3, sub = tid & 7;
      int m = m0 + r;
      bool ok = m < n_nodes;
#pragma unroll
      for (int j = 0; j < 4; ++j) {
        int c = sub * 8 + j * 64;
        bfx8 o;
        if (ok) {
          const float* p = x + (size_t)m * 256 + c;
          float4 v0 = *(const float4*)(p);
          float4 v1 = *(const float4*)(p + 4);
          o[0] = f2b(v0.x); o[1] = f2b(v0.y); o[2] = f2b(v0.z); o[3] = f2b(v0.w);
          o[4] = f2b(v1.x); o[5] = f2b(v1.y); o[6] = f2b(v1.z); o[7] = f2b(v1.w);
        } else {
          o = (bfx8){0, 0, 0, 0, 0, 0, 0, 0};
        }
        *(bfx8*)&smA[r * 264 + c] = o;
      }
    }
    __syncthreads();

    // ---- MFMA burst: barrier-free, all operands in LDS/registers ----
    fx4 acc[4][4] = {};
#pragma unroll
    for (int ks = 0; ks < 8; ++ks) {
      bfx8 af[4];
#pragma unroll
      for (int mt = 0; mt < 4; ++mt)
        af[mt] = *(const bfx8*)&smA[(mt * 16 + lr) * 264 + ks * 32 + lg * 8];
#pragma unroll
      for (int nt = 0; nt < 4; ++nt)
#pragma unroll
        for (int mt = 0; mt < 4; ++mt)
          acc[mt][nt] = __builtin_amdgcn_mfma_f32_16x16x32_bf16(af[mt], bw[nt][ks], acc[mt][nt], 0, 0, 0);
    }
    __syncthreads();                  // all waves done reading smA before smT overwrite

    // ---- epilogue: two 32-row passes through smT (alias of smA), coalesced stores.
    // Fully unrolled: acc[] must stay statically indexed (round-1 spill lesson).
#pragma unroll
    for (int h = 0; h < 2; ++h) {
#pragma unroll
      for (int mt2 = 0; mt2 < 2; ++mt2) {
        const int mt = 2 * h + mt2;
#pragma unroll
        for (int nt = 0; nt < 4; ++nt)
#pragma unroll
          for (int i = 0; i < 4; ++i) {
            int mr = mt2 * 16 + lg * 4 + i;
            int nc = n0 + nt * 16 + lr;
            smT[mr * 520 + nc] = f2b(acc[mt][nt][i] + bias[nt]);
          }
      }
      __syncthreads();
      int r = tid >> 4, cbase = (tid & 15) * 8;
      int m = m0 + h * 32 + r;
      if (m < n_nodes) {
#pragma unroll
        for (int j = 0; j < 4; ++j) {
          int c = cbase + j * 128;
          *(bfx8*)(PQ + (size_t)m * 512 + c) = *(const bfx8*)&smT[r * 520 + c];
        }
      }
      __syncthreads();
    }
  }
}

// ---------------- edge kernel (round-2 proven structure + safe micro-opts): --------
// h1=relu(P[src]+Q'[dst]); h2=relu(h1@W2^T+b2); out=h2@w3+b3.
// 256 thr / 4 waves; wave w owns n in [w*64, w*64+64); W2 frags in registers
// (bw[4][8]=128 VGPR + acc 64 AGPR, (256,2) -> no reg cap, no spill).
// Micro-opts vs round 6: perm-based round-half-up bf16 pack in the gather
// (numerics verified rounds 3-5) + next-tile index prefetch.
__launch_bounds__(256, 2)
__global__ void k_edge(const unsigned short* __restrict__ PQ,
                       const int* __restrict__ src, const int* __restrict__ dst,
                       const unsigned short* __restrict__ W2b,
                       const float* __restrict__ b2, const float* __restrict__ W3,
                       const float* __restrict__ b3, float* __restrict__ out,
                       int E, int ntiles) {
  __shared__ __align__(16) short smH[64 * 264];   // 33.8 KB, stride 264
  __shared__ float smS[4][64];
  const int tid = threadIdx.x;
  const int wave = tid >> 6, lane = tid & 63;
  const int lr = lane & 15, lg = lane >> 4;

  // W2 fragments (this wave's 64 N rows, full K=256): 4 n-tiles x 8 k-steps
  bfx8 bw[4][8];
  float b2v[4], w3v[4];
#pragma unroll
  for (int nt = 0; nt < 4; ++nt) {
    int n = wave * 64 + nt * 16 + lr;
    b2v[nt] = b2[n];
    w3v[nt] = W3[n];
#pragma unroll
    for (int ks = 0; ks < 8; ++ks)
      bw[nt][ks] = *(const bfx8*)(W2b + n * 256 + ks * 32 + lg * 8);
  }
  const float b3v = b3[0];

  const int r = tid >> 2;                 // edge row in tile (4 thr/edge)
  const int sub = tid & 3;
  const int stride = gridDim.x * E_TILE;

  // prefetch first tile's indices
  int e0 = blockIdx.x * E_TILE + r;
  int s_cur = 0, d_cur = 0;
  if (e0 < E) { s_cur = src[e0]; d_cur = dst[e0]; }

  for (int tile = blockIdx.x; tile < ntiles; tile += gridDim.x) {
    const int base = tile * E_TILE;
    const int e = base + r;
    // gather + fuse layer1: h1 = relu(P[src]+Q'[dst]) -> smH bf16 (b1 already in Q').
    // bf16 pairs as u32: shl/and extract, round-half-up pack via +0x8000+perm.
    if (e < E) {
      const unsigned* ps = (const unsigned*)(PQ + (size_t)s_cur * 512);
      const unsigned* pd = (const unsigned*)(PQ + (size_t)d_cur * 512 + 256);
#pragma unroll
      for (int it = 0; it < 8; ++it) {
        int c = sub * 8 + it * 32;
        uint4 pv = *(const uint4*)(ps + (c >> 1));
        uint4 qv = *(const uint4*)(pd + (c >> 1));
        unsigned o[4];
        const unsigned* pw = (const unsigned*)&pv;
        const unsigned* qw = (const unsigned*)&qv;
#pragma unroll
        for (int w = 0; w < 4; ++w) {
          unsigned up = pw[w], uq = qw[w];
          float slo = relu(asf(up << 16) + asf(uq << 16));
          float shi = relu(asf(up & 0xffff0000u) + asf(uq & 0xffff0000u));
          o[w] = __builtin_amdgcn_perm(asu(shi) + 0x8000u, asu(slo) + 0x8000u,
                                       0x07060302u);
        }
        *(uint4*)&smH[r * 264 + c] = make_uint4(o[0], o[1], o[2], o[3]);
      }
    } else {
#pragma unroll
      for (int it = 0; it < 8; ++it) {
        int c = sub * 8 + it * 32;
        *(uint4*)&smH[r * 264 + c] = make_uint4(0, 0, 0, 0);
      }
    }
    // issue next tile's index loads now (overlap with barrier + MFMA)
    int e_next = e + stride;
    if (e_next < E) { s_cur = src[e_next]; d_cur = dst[e_next]; }
    __syncthreads();

    // layer2 GEMM: 64M x 64N per wave, K=256
    fx4 acc[4][4] = {};
#pragma unroll
    for (int ks = 0; ks < 8; ++ks) {
      bfx8 af[4];
#pragma unroll
      for (int mt = 0; mt < 4; ++mt)
        af[mt] = *(const bfx8*)&smH[(mt * 16 + lr) * 264 + ks * 32 + lg * 8];
#pragma unroll
      for (int nt = 0; nt < 4; ++nt)
#pragma unroll
        for (int mt = 0; mt < 4; ++mt)
          acc[mt][nt] = __builtin_amdgcn_mfma_f32_16x16x32_bf16(af[mt], bw[nt][ks], acc[mt][nt], 0, 0, 0);
    }

    // epilogue: relu(acc+b2) dot w3, shfl-reduce over this wave's 64 n
#pragma unroll
    for (int mt = 0; mt < 4; ++mt)
#pragma unroll
      for (int i = 0; i < 4; ++i) {
        float p = 0.f;
#pragma unroll
        for (int nt = 0; nt < 4; ++nt)
          p += relu(acc[mt][nt][i] + b2v[nt]) * w3v[nt];
        p += __shfl_xor(p, 1);
        p += __shfl_xor(p, 2);
        p += __shfl_xor(p, 4);
        p += __shfl_xor(p, 8);
        if (lr == 0) smS[wave][mt * 16 + lg * 4 + i] = p;
      }
    __syncthreads();
    if (tid < 64) {
      int eo = base + tid;
      if (eo < E) out[eo] = smS[0][tid] + smS[1][tid] + smS[2][tid] + smS[3][tid] + b3v;
    }
    __syncthreads();
  }
}

// ---------------- fallback (if ws too small): naive fp32, 1 edge per wave ----------------
__global__ void k_fallback(const float* __restrict__ x, const int* __restrict__ src,
                           const int* __restrict__ dst, const float* __restrict__ W1,
                           const float* __restrict__ b1, const float* __restrict__ W2,
                           const float* __restrict__ b2, const float* __restrict__ W3,
                           const float* __restrict__ b3, float* __restrict__ out, int E) {
  __shared__ float smF[4][512];
  __shared__ float smG[4][256];
  int wave = threadIdx.x >> 6, lane = threadIdx.x & 63;
  int e = blockIdx.x * 4 + wave;
  bool valid = e < E;
  int ec = valid ? e : 0;
  int s = src[ec], d = dst[ec];
  for (int j = 0; j < 8; ++j) {
    int k = lane * 8 + j;
    smF[wave][k] = (k < 256) ? x[(size_t)s * 256 + k] : x[(size_t)d * 256 + k - 256];
  }
  __syncthreads();
  for (int t = 0; t < 4; ++t) {
    int n = lane + t * 64;
    float a = b1[n];
    for (int k = 0; k < 512; ++k) a += smF[wave][k] * W1[n * 512 + k];
    smG[wave][n] = relu(a);
  }
  __syncthreads();
  float p = 0.f;
  for (int t = 0; t < 4; ++t) {
    int n = lane + t * 64;
    float a = b2[n];
    for (int k = 0; k < 256; ++k) a += smG[wave][k] * W2[n * 256 + k];
    p += relu(a) * W3[n];
  }
  for (int m = 1; m < 64; m <<= 1) p += __shfl_xor(p, m);
  if (lane == 0 && valid) out[e] = p + b3[0];
}

extern "C" void kernel_launch(void* const* d_in, const int* in_sizes, int n_in,
                              void* d_out, int out_size, void* d_ws, size_t ws_size,
                              hipStream_t stream) {
  const float* x  = (const float*)d_in[0];
  const int*   src = (const int*)d_in[1];
  const int*   dst = (const int*)d_in[2];
  const float* W1 = (const float*)d_in[3];
  const float* b1 = (const float*)d_in[4];
  const float* W2 = (const float*)d_in[5];
  const float* b2 = (const float*)d_in[6];
  const float* W3 = (const float*)d_in[7];
  const float* b3 = (const float*)d_in[8];
  float* out = (float*)d_out;

  const int E = in_sizes[1];
  const int n_nodes = in_sizes[0] / 256;

  const size_t offB1 = 0;
  const size_t offW2 = (size_t)512 * 256 * 2;                 // 262144
  const size_t offPQ = offW2 + (size_t)256 * 256 * 2;         // 393216
  const size_t need = offPQ + (size_t)n_nodes * 512 * 2;      // ~51.6 MB

  if (ws_size >= need) {
    unsigned short* B1  = (unsigned short*)((char*)d_ws + offB1);
    unsigned short* W2b = (unsigned short*)((char*)d_ws + offW2);
    unsigned short* PQ  = (unsigned short*)((char*)d_ws + offPQ);
    k_prep<<<768, 256, 0, stream>>>(W1, W2, B1, W2b);
    const int ntiles_n = (n_nodes + 63) / 64;
    k_node<<<256, 512, 0, stream>>>(x, B1, b1, PQ, n_nodes, ntiles_n);
    const int ntiles = (E + E_TILE - 1) / E_TILE;
    k_edge<<<512, 256, 0, stream>>>(PQ, src, dst, W2b, b2, W3, b3, out, E, ntiles);
  } else {
    k_fallback<<<(E + 3) / 4, 256, 0, stream>>>(x, src, dst, W1, b1, W2, b2, W3, b3, out, E);
  }
}